// Round 5
// baseline (378.468 us; speedup 1.0000x reference)
//
#include <hip/hip_runtime.h>
#include <math.h>

typedef _Float16 f16;
typedef f16 f16x8 __attribute__((ext_vector_type(8)));
typedef float f32x4 __attribute__((ext_vector_type(4)));

#define Bsz   16384
#define Tobs  8
#define PREDL 12
#define MR    32   // rows per block -> grid 512 = 2 blocks/CU once regs allow

__device__ __forceinline__ float fast_sigm(float x) {
  float e = __builtin_amdgcn_exp2f(-1.44269504f * x);
  return __builtin_amdgcn_rcpf(1.f + e);
}
__device__ __forceinline__ float fast_tanh(float x) {
  float e = __builtin_amdgcn_exp2f(2.88539008f * x);  // e^(2x)
  return 1.f - 2.f * __builtin_amdgcn_rcpf(1.f + e);
}

// ---------------------------------------------------------------------------
// VGPR-form MFMA via inline asm.  The __builtin_amdgcn_mfma_* path lets the
// compiler allocate C/D (and B frags) in AGPRs; on gfx950 the unified file
// makes occupancy depend on arch+AGPR TOTAL (~148-164 in R0/R4 -> only 3
// waves/SIMD -> a second 8-wave block never fit, occupancy stuck at 22%).
// "v"-constrained asm forces everything into arch VGPRs (~<=128 total ->
// 4 waves/SIMD -> 2 blocks/CU).  Hazard handling is manual:
//   - chain head: s_nop 1 guards VALU-write -> MFMA SrcC (2 wait states)
//   - chain tail: s_nop 7 guards MFMA-D -> VALU read of the accumulator
//   - MFMA->MFMA same-accumulator chaining needs no nops (HW-supported)
//   - ds_read/global_load -> MFMA input: compiler inserts s_waitcnt (asm
//     input operands are tracked as uses)
// ---------------------------------------------------------------------------
__device__ __forceinline__ f32x4 mfma_first(f16x8 a, f16x8 b, f32x4 c) {
  asm("s_nop 1\n\tv_mfma_f32_16x16x32_f16 %0, %1, %2, %0"
      : "+v"(c) : "v"(a), "v"(b));
  return c;
}
__device__ __forceinline__ f32x4 mfma_mid(f16x8 a, f16x8 b, f32x4 c) {
  asm("v_mfma_f32_16x16x32_f16 %0, %1, %2, %0"
      : "+v"(c) : "v"(a), "v"(b));
  return c;
}
__device__ __forceinline__ f32x4 mfma_last(f16x8 a, f16x8 b, f32x4 c) {
  asm("v_mfma_f32_16x16x32_f16 %0, %1, %2, %0\n\ts_nop 7"
      : "+v"(c) : "v"(a), "v"(b));
  return c;
}

// Abuf index: [buf(2)][kt(4)][mt(2)][lane(64)][j(8)] f16  (16 KB)
#define AB(buf, kt, mt, lane, j) (((((buf)*4 + (kt))*2 + (mt))*64 + (lane))*8 + (j))
// cntA index: [t(8)][mt(2)][lane(64)][j(8)] f16            (16 KB)
#define CA(t, mt, lane, j) ((((t)*2 + (mt))*64 + (lane))*8 + (j))

// Wfrag fragment slot: [ktw(9)][w(8)][nt(4)][lane(64)][j(8)] f16
// ktw 0..3: W_hh ; ktw 4: extras [cells(16)|wio(2)|0...] ; ktw 5..8: W_eff
#define WF(ktw, w, nt, lane) ((size_t)((((ktw)*8 + (w))*4 + (nt))*64 + (lane)) * 8)

// ---------------------------------------------------------------------------
// pack_all: one single-wave block per gate-row jo (512 blocks).  (R0 layout)
// ---------------------------------------------------------------------------
__global__ __launch_bounds__(64) void pack_all(
    const float* __restrict__ W_ih, const float* __restrict__ W_hh,
    const float* __restrict__ W_in, const float* __restrict__ W_sp,
    const float* __restrict__ table,
    const float* __restrict__ b_in, const float* __restrict__ b_sp,
    const float* __restrict__ b_ih, const float* __restrict__ b_hh,
    const float* __restrict__ W_out, const float* __restrict__ b_out,
    f16* __restrict__ Wfrag, float* __restrict__ biasO,
    float* __restrict__ biasP, float* __restrict__ biasPE) {
  const int blk = blockIdx.x;            // 0..511
  const int nt = blk >> 7, w = (blk >> 4) & 7, l = blk & 15;
  const int jo = nt * 128 + w * 16 + l;  // original gate row
  const int m = threadIdx.x;             // 0..63
  __shared__ float st[256];              // hh[128] | eff[128]
  __shared__ float wspPS[32];
  __shared__ float cellsS[16];

  float a0 = W_ih[jo * 256 + m],        a1 = W_ih[jo * 256 + 64 + m];
  float s0 = W_ih[jo * 256 + 128 + m],  s1 = W_ih[jo * 256 + 192 + m];
  float hh0 = W_hh[jo * 128 + m],       hh1 = W_hh[jo * 128 + 64 + m];
  float bi0 = b_in[m], bi1 = b_in[64 + m];
  float bs0 = b_sp[m], bs1 = b_sp[64 + m];
  float wi00 = W_in[m * 2 + 0],        wi01 = W_in[m * 2 + 1];
  float wi10 = W_in[(64 + m) * 2 + 0], wi11 = W_in[(64 + m) * 2 + 1];
  float wo00 = W_out[m],       wo01 = W_out[64 + m];        // W_out[0][*]
  float wo10 = W_out[128 + m], wo11 = W_out[192 + m];       // W_out[1][*]

  auto red = [](float v) {
#pragma unroll
    for (int s = 1; s < 64; s <<= 1) v += __shfl_xor(v, s);
    return v;
  };

  // wspP[e] via butterfly reductions
#pragma unroll 4
  for (int e = 0; e < 32; ++e) {
    float wp = red(s0 * W_sp[m * 32 + e] + s1 * W_sp[(64 + m) * 32 + e]);
    if (m == e) wspPS[e] = wp;
  }
  __syncthreads();
  if (m < 16) {
    float s = 0.f;
#pragma unroll
    for (int e = 0; e < 32; ++e) s += table[m * 32 + e] * wspPS[e];
    cellsS[m] = s;
  }

  float wio0 = red(a0 * wi00 + a1 * wi10);
  float wio1 = red(a0 * wi01 + a1 * wi11);
  float dotA = red(a0 * bi0 + a1 * bi1);
  float dotS = red(s0 * bs0 + s1 * bs1);

  st[m] = hh0;
  st[64 + m] = hh1;
  st[128 + m] = hh0 + wio0 * wo00 + wio1 * wo10;
  st[192 + m] = hh1 + wio0 * wo01 + wio1 * wo11;
  __syncthreads();

  if (m < 32) {  // W_hh (which=0) and W_eff (which=1) fragment writes
    int u = m & 15, kt = u >> 2, q = u & 3;
    int which = m >> 4;
    int ktw = which ? kt + 5 : kt;
    f16x8 v;
#pragma unroll
    for (int j = 0; j < 8; ++j) v[j] = (f16)st[which * 128 + kt * 32 + q * 8 + j];
    *(f16x8*)(Wfrag + WF(ktw, w, nt, q * 16 + l)) = v;
  } else if (m < 36) {  // extras tile ktw=4, q = m-32
    int q = m - 32;
    f16x8 v;
#pragma unroll
    for (int j = 0; j < 8; ++j) {
      int kk = q * 8 + j;
      float x = (kk < 16) ? cellsS[kk] : (kk == 16 ? wio0 : (kk == 17 ? wio1 : 0.f));
      v[j] = (f16)x;
    }
    *(f16x8*)(Wfrag + WF(4, w, nt, q * 16 + l)) = v;
  } else if (m == 36) {
    int col = w * 64 + nt * 16 + l;  // permuted column index
    float base = b_ih[jo] + b_hh[jo];
    biasO[col] = base + dotA + dotS;
    float bp = base + dotA;
    biasP[col] = bp;
    biasPE[col] = bp + wio0 * b_out[0] + wio1 * b_out[1];
  }
}

// ---------------------------------------------------------------------------
// Main: 32 rows/block, 512 threads (8 waves), grid 512 -> target 2 blocks/CU.
// (512,4) + asm-VGPR MFMA: total register file use = arch only (~<=128), so
// 4 waves/SIMD fit and two blocks co-reside (16 waves/CU, 2 independent
// barrier domains).  Bx frags and the disp W_out slice are re-loaded from
// L2-resident global instead of pinned, for headroom.
// ---------------------------------------------------------------------------
__global__ __launch_bounds__(512, 4) void social_lstm_main(
    const float* __restrict__ obs, const float* __restrict__ nb,
    const f16* __restrict__ Wfrag, const float* __restrict__ biasO,
    const float* __restrict__ biasP, const float* __restrict__ biasPE,
    const float* __restrict__ W_out, const float* __restrict__ b_out,
    float* __restrict__ out) {
  __shared__ __align__(16) f16 Abuf[2 * 4 * 2 * 64 * 8];  // 16 KB
  __shared__ __align__(16) f16 cntA[8 * 2 * 64 * 8];      // 16 KB obs A-panels

  const int tid = threadIdx.x;
  const int w = tid >> 6, ln = tid & 63;
  const int q = ln >> 4, l = ln & 15;
  const int b0 = blockIdx.x * MR;

  // zero Abuf buf0 (h0 = 0) + all of cntA (channels 18..31 must be 0.0)
  for (int i = tid; i < 2048; i += 512) ((uint32_t*)Abuf)[i] = 0u;
  for (int i = tid; i < 4096; i += 512) ((uint32_t*)cntA)[i] = 0u;
  __syncthreads();

  // ---------------- fused social pooling: 16 lanes/row x 4 tracks ----------
  {
    const int r = tid >> 4;   // local row 0..31
    const int lg = tid & 15;  // lane-group within row (shfl_xor 1,2,4,8 in-row)
    const float4* orow = (const float4*)(obs + (size_t)(b0 + r) * 16);
    float4 O0 = orow[0], O1 = orow[1], O2 = orow[2], O3 = orow[3];
    float ox[8] = {O0.x, O0.z, O1.x, O1.z, O2.x, O2.z, O3.x, O3.z};
    float oy[8] = {O0.y, O0.w, O1.y, O1.w, O2.y, O2.w, O3.y, O3.w};
    unsigned long long h[8] = {0ull, 0ull, 0ull, 0ull, 0ull, 0ull, 0ull, 0ull};
#pragma unroll
    for (int half = 0; half < 2; ++half) {  // 2 halves keep transient T[] small
      float4 T[8];
#pragma unroll
      for (int jt = 0; jt < 2; ++jt) {
        int trk = lg + 16 * (half * 2 + jt);
        const float4* tr = (const float4*)(nb + ((size_t)(b0 + r) * 64 + trk) * 16);
#pragma unroll
        for (int u = 0; u < 4; ++u) T[jt * 4 + u] = tr[u];
      }
#pragma unroll
      for (int jt = 0; jt < 2; ++jt) {
        float nx[8] = {T[jt*4+0].x, T[jt*4+0].z, T[jt*4+1].x, T[jt*4+1].z,
                       T[jt*4+2].x, T[jt*4+2].z, T[jt*4+3].x, T[jt*4+3].z};
        float ny[8] = {T[jt*4+0].y, T[jt*4+0].w, T[jt*4+1].y, T[jt*4+1].w,
                       T[jt*4+2].y, T[jt*4+2].w, T[jt*4+3].y, T[jt*4+3].w};
#pragma unroll
        for (int t = 0; t < 8; ++t) {
          float rx = nx[t] - ox[t], ry = ny[t] - oy[t];
          int ix = (int)floorf(rx + rx);
          int iy = (int)floorf(ry + ry);
          ix = min(max(ix, -2), 1);
          iy = min(max(iy, -2), 1);
          int flat = (ix + 2) * 4 + (iy + 2);  // 0..15; per-lane count <= 4
          h[t] += 1ull << (flat * 4);          // 4-bit bins (max 4, no overflow)
        }
      }
    }
    auto shx = [](unsigned long long x, int msk) {
      unsigned lo = __shfl_xor((unsigned)x, msk);
      unsigned hi = __shfl_xor((unsigned)(x >> 32), msk);
      return ((unsigned long long)hi << 32) | lo;
    };
#pragma unroll
    for (int t = 0; t < 8; ++t) {
      // split to 8-bit bins BEFORE merging (sums reach 64)
      unsigned long long e0 = h[t] & 0x0F0F0F0F0F0F0F0Full;         // even cells
      unsigned long long e1 = (h[t] >> 4) & 0x0F0F0F0F0F0F0F0Full;  // odd cells
      e0 += shx(e0, 1); e1 += shx(e1, 1);
      e0 += shx(e0, 2); e1 += shx(e1, 2);
      e0 += shx(e0, 4); e1 += shx(e1, 4);
      e0 += shx(e0, 8); e1 += shx(e1, 8);
      // lane lg owns cell lg: even cells in e0 byte lg/2, odd in e1 byte lg/2
      unsigned long long src = (lg & 1) ? e1 : e0;
      unsigned cnt = (unsigned)(src >> ((lg >> 1) * 8)) & 0xFFu;
      int c = lg;
      cntA[CA(t, r >> 4, (c >> 3) * 16 + (r & 15), c & 7)] = (f16)(float)cnt;
    }
    // xy channels 16,17: lane lg<8 covers t=lg for its row
    if (lg < 8) {
      float xv = obs[(size_t)(b0 + r) * 16 + lg * 2];
      float yv = obs[(size_t)(b0 + r) * 16 + lg * 2 + 1];
      cntA[CA(lg, r >> 4, 2 * 16 + (r & 15), 0)] = (f16)xv;
      cntA[CA(lg, r >> 4, 2 * 16 + (r & 15), 1)] = (f16)yv;
    }
  }

  // persistent W_hh B fragments (64 arch VGPR).  Bx re-loaded per obs step.
  f16x8 Bh[4][4];
#pragma unroll
  for (int kt = 0; kt < 4; ++kt)
#pragma unroll
    for (int nt = 0; nt < 4; ++nt)
      Bh[kt][nt] = *(const f16x8*)(Wfrag + WF(kt, w, nt, ln));

  float creg[8];
#pragma unroll
  for (int i = 0; i < 8; ++i) creg[i] = 0.f;

  float bOr[4];
#pragma unroll
  for (int g2 = 0; g2 < 4; ++g2) bOr[g2] = biasO[w * 64 + g2 * 16 + l];

  const int hc = w * 16 + l;
  const int aw_kt = hc >> 5, aw_quad = (hc >> 3) & 3, aw_j = l & 7;

  // One mt-half of a step: acc[4] (16 regs), MFMA chain then epilogue.
  auto step_half = [&](int rb, int wb, int mt, const float* bq, bool ex, int t) {
    f32x4 a[4];
#pragma unroll
    for (int nt = 0; nt < 4; ++nt) a[nt] = (f32x4){bq[nt], bq[nt], bq[nt], bq[nt]};
    if (ex) {
      f16x8 Ax = *(const f16x8*)(&cntA[CA(t, mt, ln, 0)]);
#pragma unroll
      for (int nt = 0; nt < 4; ++nt) {
        f16x8 Bxv = *(const f16x8*)(Wfrag + WF(4, w, nt, ln));  // L2-resident
        a[nt] = mfma_first(Ax, Bxv, a[nt]);
      }
#pragma unroll
      for (int kt = 0; kt < 4; ++kt) {
        f16x8 Af = *(const f16x8*)(&Abuf[AB(rb, kt, mt, ln, 0)]);
#pragma unroll
        for (int nt = 0; nt < 4; ++nt)
          a[nt] = (kt == 3) ? mfma_last(Af, Bh[kt][nt], a[nt])
                            : mfma_mid(Af, Bh[kt][nt], a[nt]);
      }
    } else {
#pragma unroll
      for (int kt = 0; kt < 4; ++kt) {
        f16x8 Af = *(const f16x8*)(&Abuf[AB(rb, kt, mt, ln, 0)]);
#pragma unroll
        for (int nt = 0; nt < 4; ++nt)
          a[nt] = (kt == 0) ? mfma_first(Af, Bh[kt][nt], a[nt])
                : (kt == 3) ? mfma_last(Af, Bh[kt][nt], a[nt])
                            : mfma_mid(Af, Bh[kt][nt], a[nt]);
      }
    }
#pragma unroll
    for (int reg = 0; reg < 4; ++reg) {
      float p0 = a[0][reg], p1 = a[1][reg], p2 = a[2][reg], p3 = a[3][reg];
      float iv = fast_sigm(p0), fv = fast_sigm(p1);
      float gv = fast_tanh(p2), ov = fast_sigm(p3);
      int ci = mt * 4 + reg;
      float c2 = fv * creg[ci] + iv * gv;
      creg[ci] = c2;
      float hv = ov * fast_tanh(c2);
      Abuf[AB(wb, aw_kt, mt, (q * 4 + reg) + 16 * aw_quad, aw_j)] = (f16)hv;
    }
  };

  // ---------------- observation phase ----------------
#pragma unroll
  for (int t = 0; t < Tobs; ++t) {
    const int rb = t & 1, wb = rb ^ 1;
    __syncthreads();
#pragma unroll
    for (int mt = 0; mt < 2; ++mt) step_half(rb, wb, mt, bOr, true, t);
  }

  // ---------------- prediction step 0 (prev disp = 0, plain W_hh) ----------
  {
    float bPr[4];
#pragma unroll
    for (int g2 = 0; g2 < 4; ++g2) bPr[g2] = biasP[w * 64 + g2 * 16 + l];
    const int rb = Tobs & 1, wb = rb ^ 1;  // rb=0, wb=1
    __syncthreads();
#pragma unroll
    for (int mt = 0; mt < 2; ++mt) step_half(rb, wb, mt, bPr, false, 0);
  }

  // swap to W_eff + biasPE
#pragma unroll
  for (int kt = 0; kt < 4; ++kt)
#pragma unroll
    for (int nt = 0; nt < 4; ++nt)
      Bh[kt][nt] = *(const f16x8*)(Wfrag + WF(kt + 5, w, nt, ln));
  float bEr[4];
#pragma unroll
  for (int g2 = 0; g2 < 4; ++g2) bEr[g2] = biasPE[w * 64 + g2 * 16 + l];

  // disp: 8 threads per (row, jj) dot; thread covers 16 h-cols.
  // W_out slice loaded inside disp_out (1 KB, L1-resident) — not pinned.
  const int d_oi = tid >> 3, d_s8 = tid & 7;
  const int d_row = d_oi >> 1, d_jj = d_oi & 1;   // d_row 0..31
  const int d_kt = d_s8 >> 1, d_half = d_s8 & 1;  // kt seg + 16-col half
  const float d_bo = b_out[d_jj];

  auto disp_out = [&](int rbuf, int p) {
    const float4* wp = (const float4*)(W_out + d_jj * 128 + d_kt * 32 + d_half * 16);
    float4 w0 = wp[0], w1 = wp[1], w2 = wp[2], w3 = wp[3];
    float wv[16] = {w0.x, w0.y, w0.z, w0.w, w1.x, w1.y, w1.z, w1.w,
                    w2.x, w2.y, w2.z, w2.w, w3.x, w3.y, w3.z, w3.w};
    float s = 0.f;
#pragma unroll
    for (int qq = 0; qq < 2; ++qq) {
      f16x8 h8 = *(const f16x8*)(
          &Abuf[AB(rbuf, d_kt, d_row >> 4, (d_row & 15) + 16 * (2 * d_half + qq), 0)]);
#pragma unroll
      for (int u = 0; u < 8; ++u) s += wv[qq * 8 + u] * (float)h8[u];
    }
    s += __shfl_xor(s, 1);
    s += __shfl_xor(s, 2);
    s += __shfl_xor(s, 4);
    if ((tid & 7) == 0)
      out[((size_t)(b0 + d_row)) * (PREDL * 2) + p * 2 + d_jj] = s + d_bo;
  };

  // ---------------- prediction steps 1..11 (pure h recurrence) -------------
  for (int p = 1; p < PREDL; ++p) {
    const int s = Tobs + p;
    const int rb = s & 1, wb = rb ^ 1;
    __syncthreads();
    disp_out(rb, p - 1);  // h_{p-1} lives in Abuf[rb]
#pragma unroll
    for (int mt = 0; mt < 2; ++mt) step_half(rb, wb, mt, bEr, false, 0);
  }
  __syncthreads();
  disp_out((Tobs + PREDL) & 1, PREDL - 1);  // h_11 in buf 0
}

// ---------------------------------------------------------------------------
extern "C" void kernel_launch(void* const* d_in, const int* in_sizes, int n_in,
                              void* d_out, int out_size, void* d_ws, size_t ws_size,
                              hipStream_t stream) {
  const float* obs   = (const float*)d_in[0];
  const float* nbrs  = (const float*)d_in[1];
  const float* table = (const float*)d_in[2];
  const float* W_in  = (const float*)d_in[3];
  const float* b_in  = (const float*)d_in[4];
  const float* W_sp  = (const float*)d_in[5];
  const float* b_sp  = (const float*)d_in[6];
  const float* W_ih  = (const float*)d_in[7];
  const float* W_hh  = (const float*)d_in[8];
  const float* b_ih  = (const float*)d_in[9];
  const float* b_hh  = (const float*)d_in[10];
  const float* W_out = (const float*)d_in[11];
  const float* b_out = (const float*)d_in[12];
  float* out = (float*)d_out;

  // ws layout (bytes): Wfrag f16[147456] @0 (294912) | biasO @294912 |
  //                    biasP @296960 | biasPE @299008
  char* ws = (char*)d_ws;
  f16*   Wfrag  = (f16*)(ws);
  float* biasO  = (float*)(ws + 294912);
  float* biasP  = (float*)(ws + 296960);
  float* biasPE = (float*)(ws + 299008);

  pack_all<<<512, 64, 0, stream>>>(W_ih, W_hh, W_in, W_sp, table, b_in, b_sp, b_ih, b_hh,
                                   W_out, b_out, Wfrag, biasO, biasP, biasPE);
  social_lstm_main<<<Bsz / MR, 512, 0, stream>>>(obs, nbrs, Wfrag, biasO, biasP, biasPE,
                                                 W_out, b_out, out);
}

// Round 7
// 210.884 us; speedup vs baseline: 1.7947x; 1.7947x over previous
//
#include <hip/hip_runtime.h>
#include <math.h>

typedef _Float16 f16;
typedef f16 f16x8 __attribute__((ext_vector_type(8)));
typedef float f32x4 __attribute__((ext_vector_type(4)));

#define Bsz   16384
#define Tobs  8
#define PREDL 12
#define MR    32   // batch rows per block; 1024 threads, grid 512

__device__ __forceinline__ float fast_sigm(float x) {
  float e = __builtin_amdgcn_exp2f(-1.44269504f * x);
  return __builtin_amdgcn_rcpf(1.f + e);
}
__device__ __forceinline__ float fast_tanh(float x) {
  float e = __builtin_amdgcn_exp2f(2.88539008f * x);  // e^(2x)
  return 1.f - 2.f * __builtin_amdgcn_rcpf(1.f + e);
}

// ---------------------------------------------------------------------------
// TRANSPOSED-GATES layout.  gates^T = W * [h; x]:
//   A operand = weight fragments, 16 gate-rows x K32: lane holds
//     A[row = l&15][k = (l>>4)*8 + j].
//   B operand = h (or cnt) panels, K32 x 16 batch: lane holds
//     B[k = (l>>4)*8 + j][col = l&15].
//   C/D: row = (l>>4)*4 + reg, col = l&15.
// Gate-row permutation: tile (w,rt) row r <-> jo = (r&3)*128 + w*8 + rt*4 + (r>>2)
//   => lane (q = l>>4) acc reg = gate reg of h-col (w*8 + rt*4 + q), batch col.
// So each lane's f32x4 acc = {i,f,g,o} of ONE h-cell: epilogue is fully
// lane-local (R3's 8-shuffle exchange eliminated).  Builtin MFMA only.
// ---------------------------------------------------------------------------

// Hbuf: [buf(2)][ct(2)][kt(4)][lane(64)][j(8)] f16  (16 KB)  — B-operand panels
#define HB(buf, ct, kt, lane, j) (((((buf)*2 + (ct))*4 + (kt))*64 + (lane))*8 + (j))
// cntX: [t(8)][ct(2)][lane(64)][j(8)] f16           (16 KB)  — obs x-panels
#define CX(t, ct, lane, j) ((((t)*2 + (ct))*64 + (lane))*8 + (j))
// Wfrag: [ktw(9)][w(16)][rt(2)][lane(64)][j(8)] f16
// ktw 0..3: W_hh^T ; 4: extras [cells|wio|0] ; 5..8: W_eff^T
#define WF(ktw, w, rt, lane) ((size_t)((((ktw)*16 + (w))*2 + (rt))*64 + (lane)) * 8)

// ---------------------------------------------------------------------------
// pack_all: one single-wave block per gate-row jo (512 blocks).
// Writes A-operand (transposed) fragments + reg-indexed biases:
//   bias4[((w*2+rt)*4 + q)*4 + gate]
// ---------------------------------------------------------------------------
__global__ __launch_bounds__(64) void pack_all(
    const float* __restrict__ W_ih, const float* __restrict__ W_hh,
    const float* __restrict__ W_in, const float* __restrict__ W_sp,
    const float* __restrict__ table,
    const float* __restrict__ b_in, const float* __restrict__ b_sp,
    const float* __restrict__ b_ih, const float* __restrict__ b_hh,
    const float* __restrict__ W_out, const float* __restrict__ b_out,
    f16* __restrict__ Wfrag, float* __restrict__ biasO,
    float* __restrict__ biasP, float* __restrict__ biasPE) {
  const int jo = blockIdx.x;             // 0..511 gate-row
  const int g = jo >> 7, hc = jo & 127;
  const int w = hc >> 3, rt = (hc >> 2) & 1, qq = hc & 3;
  const int rowr = qq * 4 + g;           // row within the 16-row A tile
  const int m = threadIdx.x;             // 0..63
  __shared__ float wspPS[32];
  __shared__ float cellsS[16];

  float a0 = W_ih[jo * 256 + m],        a1 = W_ih[jo * 256 + 64 + m];
  float s0 = W_ih[jo * 256 + 128 + m],  s1 = W_ih[jo * 256 + 192 + m];
  float hh0 = W_hh[jo * 128 + m],       hh1 = W_hh[jo * 128 + 64 + m];
  float bi0 = b_in[m], bi1 = b_in[64 + m];
  float bs0 = b_sp[m], bs1 = b_sp[64 + m];
  float wi00 = W_in[m * 2 + 0],        wi01 = W_in[m * 2 + 1];
  float wi10 = W_in[(64 + m) * 2 + 0], wi11 = W_in[(64 + m) * 2 + 1];

  auto red = [](float v) {
#pragma unroll
    for (int s = 1; s < 64; s <<= 1) v += __shfl_xor(v, s);
    return v;
  };

  // wspP[e] via butterfly reductions
#pragma unroll 4
  for (int e = 0; e < 32; ++e) {
    float wp = red(s0 * W_sp[m * 32 + e] + s1 * W_sp[(64 + m) * 32 + e]);
    if (m == e) wspPS[e] = wp;
  }
  __syncthreads();
  if (m < 16) {
    float s = 0.f;
#pragma unroll
    for (int e = 0; e < 32; ++e) s += table[m * 32 + e] * wspPS[e];
    cellsS[m] = s;
  }

  float wio0 = red(a0 * wi00 + a1 * wi10);
  float wio1 = red(a0 * wi01 + a1 * wi11);
  float dotA = red(a0 * bi0 + a1 * bi1);
  float dotS = red(s0 * bs0 + s1 * bs1);

  // W_eff row = W_hh row + wio (x) W_out
  float eff0 = hh0 + wio0 * W_out[m]      + wio1 * W_out[128 + m];
  float eff1 = hh1 + wio0 * W_out[64 + m] + wio1 * W_out[192 + m];

  // A-frag writes: element k of row jo -> Wfrag[kt][w][rt][((k&31)>>3)*16+rowr][k&7]
  const int lane_w = ((m >> 3) & 3) * 16 + rowr;  // same for k=m and k=m+64
  const int j_w = m & 7, kh = m >> 5;             // kh in {0,1}
  Wfrag[WF(kh,     w, rt, lane_w) + j_w] = (f16)hh0;   // k = m      (kt 0,1)
  Wfrag[WF(2 + kh, w, rt, lane_w) + j_w] = (f16)hh1;   // k = m+64   (kt 2,3)
  Wfrag[WF(5 + kh, w, rt, lane_w) + j_w] = (f16)eff0;  // W_eff kt 0,1
  Wfrag[WF(7 + kh, w, rt, lane_w) + j_w] = (f16)eff1;  // W_eff kt 2,3

  if (m < 32) {  // extras tile (K'=32): cells(16) | wio(2) | 0...
    float x = (m < 16) ? cellsS[m] : (m == 16 ? wio0 : (m == 17 ? wio1 : 0.f));
    Wfrag[WF(4, w, rt, (m >> 3) * 16 + rowr) + (m & 7)] = (f16)x;
  }
  if (m == 36) {
    const int idx = ((w * 2 + rt) * 4 + qq) * 4 + g;  // float4-slot*4 + gate
    const float base = b_ih[jo] + b_hh[jo];
    biasO[idx] = base + dotA + dotS;
    biasP[idx] = base + dotA;
    biasPE[idx] = base + dotA + wio0 * b_out[0] + wio1 * b_out[1];
  }
}

// ---------------------------------------------------------------------------
// Main: 32 rows/block, 1024 threads (16 waves), grid 512.
// Wave w: gate-rows for h-cols w*8..w*8+7 (2 row-tiles) x 32 batch (2 col-
// tiles).  Per step: 8 ds_read_b128 + 16 MFMA (4 indep 4-deep chains) +
// 4 lane-local epilogues + 4 f16 LDS writes.  No shuffles, no asm.
// ---------------------------------------------------------------------------
__global__ __launch_bounds__(1024, 4) void social_lstm_main(
    const float* __restrict__ obs, const float* __restrict__ nb,
    const f16* __restrict__ Wfrag, const float* __restrict__ biasO,
    const float* __restrict__ biasP, const float* __restrict__ biasPE,
    const float* __restrict__ W_out, const float* __restrict__ b_out,
    float* __restrict__ out) {
  __shared__ __align__(16) f16 Hbuf[2 * 2 * 4 * 64 * 8];  // 16 KB
  __shared__ __align__(16) f16 cntX[8 * 2 * 64 * 8];      // 16 KB

  const int tid = threadIdx.x;
  const int w = tid >> 6, ln = tid & 63;
  const int q = ln >> 4, c = ln & 15;
  const int b0 = blockIdx.x * MR;

  // zero Hbuf buf0 (h0 = 0) + all of cntX (channels 18..31 must be 0)
  for (int i = tid; i < 2048; i += 1024) ((uint32_t*)Hbuf)[i] = 0u;
  for (int i = tid; i < 8192; i += 1024) ((uint32_t*)cntX)[i] = 0u;
  __syncthreads();

  // ---------------- fused social pooling: 32 lanes/row x 2 tracks ----------
  {
    const int r = tid >> 5;   // local row 0..31
    const int lg = tid & 31;  // 32-lane group stays inside a wave half
    const float4* orow = (const float4*)(obs + (size_t)(b0 + r) * 16);
    float4 O0 = orow[0], O1 = orow[1], O2 = orow[2], O3 = orow[3];
    float ox[8] = {O0.x, O0.z, O1.x, O1.z, O2.x, O2.z, O3.x, O3.z};
    float oy[8] = {O0.y, O0.w, O1.y, O1.w, O2.y, O2.w, O3.y, O3.w};
    unsigned long long h[8] = {0ull, 0ull, 0ull, 0ull, 0ull, 0ull, 0ull, 0ull};
#pragma unroll
    for (int jt = 0; jt < 2; ++jt) {
      int trk = lg + 32 * jt;
      const float4* tr = (const float4*)(nb + ((size_t)(b0 + r) * 64 + trk) * 16);
      float4 T0 = tr[0], T1 = tr[1], T2 = tr[2], T3 = tr[3];
      float nx[8] = {T0.x, T0.z, T1.x, T1.z, T2.x, T2.z, T3.x, T3.z};
      float ny[8] = {T0.y, T0.w, T1.y, T1.w, T2.y, T2.w, T3.y, T3.w};
#pragma unroll
      for (int t = 0; t < 8; ++t) {
        float rx = nx[t] - ox[t], ry = ny[t] - oy[t];
        int ix = (int)floorf(rx + rx);
        int iy = (int)floorf(ry + ry);
        ix = min(max(ix, -2), 1);
        iy = min(max(iy, -2), 1);
        int flat = (ix + 2) * 4 + (iy + 2);  // 0..15; per-lane count <= 2
        h[t] += 1ull << (flat * 4);          // 4-bit bins, no overflow
      }
    }
    auto shx = [](unsigned long long x, int msk) {
      unsigned lo = __shfl_xor((unsigned)x, msk);
      unsigned hi = __shfl_xor((unsigned)(x >> 32), msk);
      return ((unsigned long long)hi << 32) | lo;
    };
#pragma unroll
    for (int t = 0; t < 8; ++t) {
      // split to 8-bit bins BEFORE merging (sums reach 64)
      unsigned long long e0 = h[t] & 0x0F0F0F0F0F0F0F0Full;         // even cells
      unsigned long long e1 = (h[t] >> 4) & 0x0F0F0F0F0F0F0F0Full;  // odd cells
      e0 += shx(e0, 1);  e1 += shx(e1, 1);
      e0 += shx(e0, 2);  e1 += shx(e1, 2);
      e0 += shx(e0, 4);  e1 += shx(e1, 4);
      e0 += shx(e0, 8);  e1 += shx(e1, 8);
      e0 += shx(e0, 16); e1 += shx(e1, 16);
      if (lg < 16) {  // lane lg owns cell lg
        unsigned long long src = (lg & 1) ? e1 : e0;
        unsigned cnt = (unsigned)(src >> ((lg >> 1) * 8)) & 0xFFu;
        cntX[CX(t, r >> 4, (lg >> 3) * 16 + (r & 15), lg & 7)] = (f16)(float)cnt;
      }
    }
    // xy channels 16,17: lane lg<8 covers t=lg for its row
    if (lg < 8) {
      float xv = obs[(size_t)(b0 + r) * 16 + lg * 2];
      float yv = obs[(size_t)(b0 + r) * 16 + lg * 2 + 1];
      cntX[CX(lg, r >> 4, 2 * 16 + (r & 15), 0)] = (f16)xv;
      cntX[CX(lg, r >> 4, 2 * 16 + (r & 15), 1)] = (f16)yv;
    }
  }

  // persistent W_hh^T A-fragments: 2 rt x 4 kt = 32 VGPR
  f16x8 Wh[2][4];
#pragma unroll
  for (int rt = 0; rt < 2; ++rt)
#pragma unroll
    for (int kt = 0; kt < 4; ++kt)
      Wh[rt][kt] = *(const f16x8*)(Wfrag + WF(kt, w, rt, ln));

  float creg[4] = {0.f, 0.f, 0.f, 0.f};
  const int ktw_i = w >> 2;            // Hbuf kt of this wave's h-cols
  const int lnw = (w & 3) * 16 + c;    // Hbuf lane of this wave's h-writes
  const int bi0i = (w * 2 + 0) * 4 + q, bi1i = (w * 2 + 1) * 4 + q;

  auto epi = [&](f32x4 a, int rt, int ct, int wb) {
    float iv = fast_sigm(a[0]), fv = fast_sigm(a[1]);
    float gv = fast_tanh(a[2]), ov = fast_sigm(a[3]);
    int ci = rt * 2 + ct;
    float c2 = fv * creg[ci] + iv * gv;
    creg[ci] = c2;
    float hv = ov * fast_tanh(c2);
    Hbuf[HB(wb, ct, ktw_i, lnw, rt * 4 + q)] = (f16)hv;
  };

  auto hh_chain = [&](int rb, f32x4& a00, f32x4& a01, f32x4& a10, f32x4& a11) {
#pragma unroll
    for (int kt = 0; kt < 4; ++kt) {
      f16x8 h0 = *(const f16x8*)&Hbuf[HB(rb, 0, kt, ln, 0)];
      f16x8 h1 = *(const f16x8*)&Hbuf[HB(rb, 1, kt, ln, 0)];
      a00 = __builtin_amdgcn_mfma_f32_16x16x32_f16(Wh[0][kt], h0, a00, 0, 0, 0);
      a01 = __builtin_amdgcn_mfma_f32_16x16x32_f16(Wh[0][kt], h1, a01, 0, 0, 0);
      a10 = __builtin_amdgcn_mfma_f32_16x16x32_f16(Wh[1][kt], h0, a10, 0, 0, 0);
      a11 = __builtin_amdgcn_mfma_f32_16x16x32_f16(Wh[1][kt], h1, a11, 0, 0, 0);
    }
  };

  // ---------------- observation phase ----------------
  {
    f16x8 Bx0 = *(const f16x8*)(Wfrag + WF(4, w, 0, ln));  // obs-only, 8 VGPR
    f16x8 Bx1 = *(const f16x8*)(Wfrag + WF(4, w, 1, ln));
#pragma unroll
    for (int t = 0; t < Tobs; ++t) {
      const int rb = t & 1, wb = rb ^ 1;
      __syncthreads();
      float4 bv0 = ((const float4*)biasO)[bi0i];
      float4 bv1 = ((const float4*)biasO)[bi1i];
      f32x4 a00 = (f32x4){bv0.x, bv0.y, bv0.z, bv0.w}, a01 = a00;
      f32x4 a10 = (f32x4){bv1.x, bv1.y, bv1.z, bv1.w}, a11 = a10;
      f16x8 c0 = *(const f16x8*)&cntX[CX(t, 0, ln, 0)];
      f16x8 c1 = *(const f16x8*)&cntX[CX(t, 1, ln, 0)];
      a00 = __builtin_amdgcn_mfma_f32_16x16x32_f16(Bx0, c0, a00, 0, 0, 0);
      a01 = __builtin_amdgcn_mfma_f32_16x16x32_f16(Bx0, c1, a01, 0, 0, 0);
      a10 = __builtin_amdgcn_mfma_f32_16x16x32_f16(Bx1, c0, a10, 0, 0, 0);
      a11 = __builtin_amdgcn_mfma_f32_16x16x32_f16(Bx1, c1, a11, 0, 0, 0);
      hh_chain(rb, a00, a01, a10, a11);
      epi(a00, 0, 0, wb); epi(a01, 0, 1, wb);
      epi(a10, 1, 0, wb); epi(a11, 1, 1, wb);
    }
  }

  // ---------------- prediction step 0 (prev disp = 0, plain W_hh) ----------
  {
    const int rb = Tobs & 1, wb = rb ^ 1;  // rb=0, wb=1
    __syncthreads();
    float4 bv0 = ((const float4*)biasP)[bi0i];
    float4 bv1 = ((const float4*)biasP)[bi1i];
    f32x4 a00 = (f32x4){bv0.x, bv0.y, bv0.z, bv0.w}, a01 = a00;
    f32x4 a10 = (f32x4){bv1.x, bv1.y, bv1.z, bv1.w}, a11 = a10;
    hh_chain(rb, a00, a01, a10, a11);
    epi(a00, 0, 0, wb); epi(a01, 0, 1, wb);
    epi(a10, 1, 0, wb); epi(a11, 1, 1, wb);
  }

  // swap to W_eff^T
#pragma unroll
  for (int rt = 0; rt < 2; ++rt)
#pragma unroll
    for (int kt = 0; kt < 4; ++kt)
      Wh[rt][kt] = *(const f16x8*)(Wfrag + WF(5 + kt, w, rt, ln));

  // disp: 16 threads per (row, jj); thread covers 8 h-cols (hc = d_s*8+u)
  const int d_oi = tid >> 4, d_s = tid & 15;
  const int d_row = d_oi >> 1, d_jj = d_oi & 1;  // d_row 0..31
  const float d_bo = b_out[d_jj];

  auto disp_out = [&](int rbuf, int p) {
    const float4* wp = (const float4*)(W_out + d_jj * 128 + d_s * 8);
    float4 w0 = wp[0], w1 = wp[1];
    f16x8 h8 = *(const f16x8*)&Hbuf[
        HB(rbuf, d_row >> 4, d_s >> 2, (d_s & 3) * 16 + (d_row & 15), 0)];
    float s = w0.x * (float)h8[0] + w0.y * (float)h8[1] +
              w0.z * (float)h8[2] + w0.w * (float)h8[3] +
              w1.x * (float)h8[4] + w1.y * (float)h8[5] +
              w1.z * (float)h8[6] + w1.w * (float)h8[7];
    s += __shfl_xor(s, 1);
    s += __shfl_xor(s, 2);
    s += __shfl_xor(s, 4);
    s += __shfl_xor(s, 8);
    if ((tid & 15) == 0)
      out[(size_t)(b0 + d_row) * (PREDL * 2) + p * 2 + d_jj] = s + d_bo;
  };

  // ---------------- prediction steps 1..11 (pure h recurrence) -------------
  for (int p = 1; p < PREDL; ++p) {
    const int st = Tobs + p;
    const int rb = st & 1, wb = rb ^ 1;
    __syncthreads();
    disp_out(rb, p - 1);  // h_{p-1} lives in Hbuf[rb]
    float4 bv0 = ((const float4*)biasPE)[bi0i];
    float4 bv1 = ((const float4*)biasPE)[bi1i];
    f32x4 a00 = (f32x4){bv0.x, bv0.y, bv0.z, bv0.w}, a01 = a00;
    f32x4 a10 = (f32x4){bv1.x, bv1.y, bv1.z, bv1.w}, a11 = a10;
    hh_chain(rb, a00, a01, a10, a11);
    epi(a00, 0, 0, wb); epi(a01, 0, 1, wb);
    epi(a10, 1, 0, wb); epi(a11, 1, 1, wb);
  }
  __syncthreads();
  disp_out((Tobs + PREDL) & 1, PREDL - 1);  // h_11 in buf 0
}

// ---------------------------------------------------------------------------
extern "C" void kernel_launch(void* const* d_in, const int* in_sizes, int n_in,
                              void* d_out, int out_size, void* d_ws, size_t ws_size,
                              hipStream_t stream) {
  const float* obs   = (const float*)d_in[0];
  const float* nbrs  = (const float*)d_in[1];
  const float* table = (const float*)d_in[2];
  const float* W_in  = (const float*)d_in[3];
  const float* b_in  = (const float*)d_in[4];
  const float* W_sp  = (const float*)d_in[5];
  const float* b_sp  = (const float*)d_in[6];
  const float* W_ih  = (const float*)d_in[7];
  const float* W_hh  = (const float*)d_in[8];
  const float* b_ih  = (const float*)d_in[9];
  const float* b_hh  = (const float*)d_in[10];
  const float* W_out = (const float*)d_in[11];
  const float* b_out = (const float*)d_in[12];
  float* out = (float*)d_out;

  // ws layout (bytes): Wfrag f16[147456] @0 (294912) | biasO @294912 |
  //                    biasP @296960 | biasPE @299008   (each 2048 B)
  char* ws = (char*)d_ws;
  f16*   Wfrag  = (f16*)(ws);
  float* biasO  = (float*)(ws + 294912);
  float* biasP  = (float*)(ws + 296960);
  float* biasPE = (float*)(ws + 299008);

  pack_all<<<512, 64, 0, stream>>>(W_ih, W_hh, W_in, W_sp, table, b_in, b_sp, b_ih, b_hh,
                                   W_out, b_out, Wfrag, biasO, biasP, biasPE);
  social_lstm_main<<<Bsz / MR, 1024, 0, stream>>>(obs, nbrs, Wfrag, biasO, biasP, biasPE,
                                                  W_out, b_out, out);
}

// Round 8
// 205.064 us; speedup vs baseline: 1.8456x; 1.0284x over previous
//
#include <hip/hip_runtime.h>
#include <math.h>

typedef _Float16 f16;
typedef f16 f16x2 __attribute__((ext_vector_type(2)));
typedef f16 f16x8 __attribute__((ext_vector_type(8)));
typedef float f32x4 __attribute__((ext_vector_type(4)));

#define Bsz   16384
#define Tobs  8
#define PREDL 12
#define MR    64   // rows per block (2 groups of 32); grid 256 = 1 block/CU

__device__ __forceinline__ float fast_sigm(float x) {
  float e = __builtin_amdgcn_exp2f(-1.44269504f * x);
  return __builtin_amdgcn_rcpf(1.f + e);
}
__device__ __forceinline__ float fast_tanh(float x) {
  float e = __builtin_amdgcn_exp2f(2.88539008f * x);  // e^(2x)
  return 1.f - 2.f * __builtin_amdgcn_rcpf(1.f + e);
}

// ---------------------------------------------------------------------------
// TRANSPOSED-GATES + DUAL-GROUP design.
//   gates^T = W * [h;x]; A = weight frags (lane: A[row=l&15][k=(l>>4)*8+j]),
//   B = h panels (lane: B[k=(l>>4)*8+j][col=l&15]), C/D row=(l>>4)*4+reg.
//   Gate-row perm: tile (w,rt) row r=q*4+g <-> gate g of hcol w*8+rt*4+q
//   => lane's f32x4 acc = {i,f,g,o} of ONE h-cell (lane-local epilogue).
//   K-dim perm pi(hcol): hcol=w*8+rt*4+q -> k=w*8+2q+rt, so a lane's two
//   h outputs (rt=0,1) are k-adjacent => ONE f16x2 LDS store (was 4 b16,
//   3x bank conflicts in R7).  W_out is pre-permuted (W_outP) to match.
// Why grid 256 / 2 groups: 1024-thr blocks can never co-reside (16 waves),
// so grid 512 (R3/R7) ran 2 sequential block-waves = 40 serial steps/CU.
// Here: 20 steps/CU, 16 waves, and each wave interleaves TWO independent
// group-chains per step (shared Wh regs) to fill MFMA/trans latency.
// ---------------------------------------------------------------------------

// Wfrag: [ktw(9)][w(16)][rt(2)][lane(64)][j(8)] f16
// ktw 0..3: W_hh^T ; 4: extras [cells|wio|0] ; 5..8: W_eff^T
#define WF(ktw, w, rt, lane) ((size_t)((((ktw)*16 + (w))*2 + (rt))*64 + (lane)) * 8)

// ---------------------------------------------------------------------------
// pack_all: one single-wave block per gate-row jo (512 blocks).
// ---------------------------------------------------------------------------
__global__ __launch_bounds__(64) void pack_all(
    const float* __restrict__ W_ih, const float* __restrict__ W_hh,
    const float* __restrict__ W_in, const float* __restrict__ W_sp,
    const float* __restrict__ table,
    const float* __restrict__ b_in, const float* __restrict__ b_sp,
    const float* __restrict__ b_ih, const float* __restrict__ b_hh,
    const float* __restrict__ W_out, const float* __restrict__ b_out,
    f16* __restrict__ Wfrag, float* __restrict__ biasO,
    float* __restrict__ biasP, float* __restrict__ biasPE,
    float* __restrict__ W_outP) {
  const int jo = blockIdx.x;             // 0..511 gate-row
  const int g = jo >> 7, hc = jo & 127;
  const int w = hc >> 3, rt = (hc >> 2) & 1, qq = hc & 3;
  const int rowr = qq * 4 + g;           // row within the 16-row A tile
  const int m = threadIdx.x;             // 0..63
  __shared__ float wspPS[32];
  __shared__ float cellsS[16];

  float a0 = W_ih[jo * 256 + m],        a1 = W_ih[jo * 256 + 64 + m];
  float s0 = W_ih[jo * 256 + 128 + m],  s1 = W_ih[jo * 256 + 192 + m];
  float hh0 = W_hh[jo * 128 + m],       hh1 = W_hh[jo * 128 + 64 + m];
  float bi0 = b_in[m], bi1 = b_in[64 + m];
  float bs0 = b_sp[m], bs1 = b_sp[64 + m];
  float wi00 = W_in[m * 2 + 0],        wi01 = W_in[m * 2 + 1];
  float wi10 = W_in[(64 + m) * 2 + 0], wi11 = W_in[(64 + m) * 2 + 1];

  auto red = [](float v) {
#pragma unroll
    for (int s = 1; s < 64; s <<= 1) v += __shfl_xor(v, s);
    return v;
  };

  // wspP[e] via butterfly reductions
#pragma unroll 4
  for (int e = 0; e < 32; ++e) {
    float wp = red(s0 * W_sp[m * 32 + e] + s1 * W_sp[(64 + m) * 32 + e]);
    if (m == e) wspPS[e] = wp;
  }
  __syncthreads();
  if (m < 16) {
    float s = 0.f;
#pragma unroll
    for (int e = 0; e < 32; ++e) s += table[m * 32 + e] * wspPS[e];
    cellsS[m] = s;
  }

  float wio0 = red(a0 * wi00 + a1 * wi10);
  float wio1 = red(a0 * wi01 + a1 * wi11);
  float dotA = red(a0 * bi0 + a1 * bi1);
  float dotS = red(s0 * bs0 + s1 * bs1);

  // W_eff row = W_hh row + wio (x) W_out
  float eff0 = hh0 + wio0 * W_out[m]      + wio1 * W_out[128 + m];
  float eff1 = hh1 + wio0 * W_out[64 + m] + wio1 * W_out[192 + m];

  // K permutation: h index m -> slot km; (m+64) -> km+64
  const int km = (m & 0x78) | (2 * (m & 3) + ((m >> 2) & 1));
  const int lane_w = ((km >> 3) & 3) * 16 + rowr;
  const int j_w = km & 7, kh = km >> 5;  // kh in {0,1}
  Wfrag[WF(kh,     w, rt, lane_w) + j_w] = (f16)hh0;   // k = km      (kt 0,1)
  Wfrag[WF(2 + kh, w, rt, lane_w) + j_w] = (f16)hh1;   // k = km+64   (kt 2,3)
  Wfrag[WF(5 + kh, w, rt, lane_w) + j_w] = (f16)eff0;  // W_eff kt 0,1
  Wfrag[WF(7 + kh, w, rt, lane_w) + j_w] = (f16)eff1;  // W_eff kt 2,3

  if (m < 32) {  // extras tile (K'=32, unpermuted): cells(16) | wio(2) | 0...
    float x = (m < 16) ? cellsS[m] : (m == 16 ? wio0 : (m == 17 ? wio1 : 0.f));
    Wfrag[WF(4, w, rt, (m >> 3) * 16 + rowr) + (m & 7)] = (f16)x;
  }
  if (m == 36) {
    const int idx = ((w * 2 + rt) * 4 + qq) * 4 + g;  // float4-slot*4 + gate
    const float base = b_ih[jo] + b_hh[jo];
    biasO[idx] = base + dotA + dotS;
    biasP[idx] = base + dotA;
    biasPE[idx] = base + dotA + wio0 * b_out[0] + wio1 * b_out[1];
  }
  if (jo == 0) {  // permuted W_out copy for the disp phase
    W_outP[km]            = W_out[m];
    W_outP[km + 64]       = W_out[m + 64];
    W_outP[128 + km]      = W_out[128 + m];
    W_outP[128 + km + 64] = W_out[128 + m + 64];
  }
}

// ---------------------------------------------------------------------------
// Main: 64 rows/block (2 groups of 32), 1024 threads (16 waves), grid 256.
// Per step per wave: 2x{8 ds_read_b128 + 16 MFMA} + 8 lane-local cells +
// 4 packed f16x2 writes; ONE barrier.  Shared Wh (32 regs) + 2x16 acc.
// ---------------------------------------------------------------------------
__global__ __launch_bounds__(1024) void social_lstm_main(
    const float* __restrict__ obs, const float* __restrict__ nb,
    const f16* __restrict__ Wfrag, const float* __restrict__ biasO,
    const float* __restrict__ biasP, const float* __restrict__ biasPE,
    const float* __restrict__ W_outP, const float* __restrict__ b_out,
    float* __restrict__ out) {
  __shared__ __align__(16) f16 Hbuf[2][2][2][4][64][8];  // [G][buf][ct][kt][ln][j] 32 KB
  __shared__ __align__(16) f16 cntX[2][8][2][64][8];     // [G][t][ct][ln][j]      32 KB

  const int tid = threadIdx.x;
  const int w = tid >> 6, ln = tid & 63;
  const int q = ln >> 4, c = ln & 15;
  const int whi = w >> 2, wlo = w & 3;
  const int b0 = blockIdx.x * MR;

  // zero all of Hbuf (h0 = 0) and cntX (k' slots 18..31 must be 0)
  for (int i = tid; i < 16384; i += 1024) {
    ((uint32_t*)Hbuf)[i] = 0u;
    ((uint32_t*)cntX)[i] = 0u;
  }
  __syncthreads();

  // ---------------- fused social pooling: 16 lanes/row x 4 tracks ----------
  {
    const int r = tid >> 4;   // local row 0..63
    const int lg = tid & 15;  // lane-group within row (shfl_xor 1,2,4,8 in-row)
    const int pG = r >> 5, prr = r & 31;
    const float4* orow = (const float4*)(obs + (size_t)(b0 + r) * 16);
    float4 O0 = orow[0], O1 = orow[1], O2 = orow[2], O3 = orow[3];
    float ox[8] = {O0.x, O0.z, O1.x, O1.z, O2.x, O2.z, O3.x, O3.z};
    float oy[8] = {O0.y, O0.w, O1.y, O1.w, O2.y, O2.w, O3.y, O3.w};
    unsigned long long h[8] = {0ull, 0ull, 0ull, 0ull, 0ull, 0ull, 0ull, 0ull};
#pragma unroll
    for (int jt = 0; jt < 4; ++jt) {  // 4 single-track passes: small transients
      int trk = lg + 16 * jt;
      const float4* tr = (const float4*)(nb + ((size_t)(b0 + r) * 64 + trk) * 16);
      float4 T0 = tr[0], T1 = tr[1], T2 = tr[2], T3 = tr[3];
      float nx[8] = {T0.x, T0.z, T1.x, T1.z, T2.x, T2.z, T3.x, T3.z};
      float ny[8] = {T0.y, T0.w, T1.y, T1.w, T2.y, T2.w, T3.y, T3.w};
#pragma unroll
      for (int t = 0; t < 8; ++t) {
        float rx = nx[t] - ox[t], ry = ny[t] - oy[t];
        int ix = (int)floorf(rx + rx);
        int iy = (int)floorf(ry + ry);
        ix = min(max(ix, -2), 1);
        iy = min(max(iy, -2), 1);
        int flat = (ix + 2) * 4 + (iy + 2);  // 0..15; per-lane count <= 4
        h[t] += 1ull << (flat * 4);          // 4-bit bins, no overflow
      }
    }
    auto shx = [](unsigned long long x, int msk) {
      unsigned lo = __shfl_xor((unsigned)x, msk);
      unsigned hi = __shfl_xor((unsigned)(x >> 32), msk);
      return ((unsigned long long)hi << 32) | lo;
    };
#pragma unroll
    for (int t = 0; t < 8; ++t) {
      // split to 8-bit bins BEFORE merging (sums reach 64)
      unsigned long long e0 = h[t] & 0x0F0F0F0F0F0F0F0Full;         // even cells
      unsigned long long e1 = (h[t] >> 4) & 0x0F0F0F0F0F0F0F0Full;  // odd cells
      e0 += shx(e0, 1); e1 += shx(e1, 1);
      e0 += shx(e0, 2); e1 += shx(e1, 2);
      e0 += shx(e0, 4); e1 += shx(e1, 4);
      e0 += shx(e0, 8); e1 += shx(e1, 8);
      // lane lg owns cell lg
      unsigned long long src = (lg & 1) ? e1 : e0;
      unsigned cnt = (unsigned)(src >> ((lg >> 1) * 8)) & 0xFFu;
      cntX[pG][t][prr >> 4][(lg >> 3) * 16 + (prr & 15)][lg & 7] = (f16)(float)cnt;
    }
    // xy channels k'=16,17: lane lg<8 covers t=lg for its row
    if (lg < 8) {
      float xv = obs[(size_t)(b0 + r) * 16 + lg * 2];
      float yv = obs[(size_t)(b0 + r) * 16 + lg * 2 + 1];
      cntX[pG][lg][prr >> 4][2 * 16 + (prr & 15)][0] = (f16)xv;
      cntX[pG][lg][prr >> 4][2 * 16 + (prr & 15)][1] = (f16)yv;
    }
  }

  // persistent W_hh^T A-fragments (shared by both groups): 2 rt x 4 kt = 32
  f16x8 Wh[2][4];
#pragma unroll
  for (int rt = 0; rt < 2; ++rt)
#pragma unroll
    for (int kt = 0; kt < 4; ++kt)
      Wh[rt][kt] = *(const f16x8*)(Wfrag + WF(kt, w, rt, ln));

  float cr[8];   // creg[G][rt][ct] = cr[G*4 + rt*2 + ct], all indices constant
#pragma unroll
  for (int i = 0; i < 8; ++i) cr[i] = 0.f;

  auto ldbias = [&](const float* bp, f32x4& v0, f32x4& v1) {
    float4 t0 = ((const float4*)bp)[(w * 2 + 0) * 4 + q];
    float4 t1 = ((const float4*)bp)[(w * 2 + 1) * 4 + q];
    v0 = (f32x4){t0.x, t0.y, t0.z, t0.w};
    v1 = (f32x4){t1.x, t1.y, t1.z, t1.w};
  };

  auto mf = [](f16x8 a, f16x8 b, f32x4 cc) {
    return __builtin_amdgcn_mfma_f32_16x16x32_f16(a, b, cc, 0, 0, 0);
  };

  auto cell = [&](const f32x4& a, float& ccst) {
    float iv = fast_sigm(a[0]), fv = fast_sigm(a[1]);
    float gv = fast_tanh(a[2]), ov = fast_sigm(a[3]);
    ccst = fv * ccst + iv * gv;
    return ov * fast_tanh(ccst);
  };

  f16x8 Bx0 = *(const f16x8*)(Wfrag + WF(4, w, 0, ln));  // obs extras A-frags
  f16x8 Bx1 = *(const f16x8*)(Wfrag + WF(4, w, 1, ln));

  f32x4 bv0, bv1;
  ldbias(biasO, bv0, bv1);

  // one full step for both groups (G unrolled; all LDS indices constant-G)
  auto step = [&](int rb, int wb, bool ex, int t) {
    f32x4 A00 = bv0, A01 = bv0, A10 = bv1, A11 = bv1;   // group 0
    f32x4 B00 = bv0, B01 = bv0, B10 = bv1, B11 = bv1;   // group 1
    if (ex) {
      f16x8 ca0 = *(const f16x8*)&cntX[0][t][0][ln][0];
      f16x8 ca1 = *(const f16x8*)&cntX[0][t][1][ln][0];
      A00 = mf(Bx0, ca0, A00); A01 = mf(Bx0, ca1, A01);
      A10 = mf(Bx1, ca0, A10); A11 = mf(Bx1, ca1, A11);
      f16x8 cb0 = *(const f16x8*)&cntX[1][t][0][ln][0];
      f16x8 cb1 = *(const f16x8*)&cntX[1][t][1][ln][0];
      B00 = mf(Bx0, cb0, B00); B01 = mf(Bx0, cb1, B01);
      B10 = mf(Bx1, cb0, B10); B11 = mf(Bx1, cb1, B11);
    }
#pragma unroll
    for (int kt = 0; kt < 4; ++kt) {
      f16x8 h0 = *(const f16x8*)&Hbuf[0][rb][0][kt][ln][0];
      f16x8 h1 = *(const f16x8*)&Hbuf[0][rb][1][kt][ln][0];
      A00 = mf(Wh[0][kt], h0, A00); A01 = mf(Wh[0][kt], h1, A01);
      A10 = mf(Wh[1][kt], h0, A10); A11 = mf(Wh[1][kt], h1, A11);
    }
#pragma unroll
    for (int kt = 0; kt < 4; ++kt) {
      f16x8 h0 = *(const f16x8*)&Hbuf[1][rb][0][kt][ln][0];
      f16x8 h1 = *(const f16x8*)&Hbuf[1][rb][1][kt][ln][0];
      B00 = mf(Wh[0][kt], h0, B00); B01 = mf(Wh[0][kt], h1, B01);
      B10 = mf(Wh[1][kt], h0, B10); B11 = mf(Wh[1][kt], h1, B11);
    }
    // epilogues: lane-local; rt pair packed into one f16x2 (k = w*8+2q+rt)
    {
      f16x2 pk;
      pk[0] = (f16)cell(A00, cr[0]); pk[1] = (f16)cell(A10, cr[2]);
      *(f16x2*)&Hbuf[0][wb][0][whi][wlo * 16 + c][2 * q] = pk;
      pk[0] = (f16)cell(A01, cr[1]); pk[1] = (f16)cell(A11, cr[3]);
      *(f16x2*)&Hbuf[0][wb][1][whi][wlo * 16 + c][2 * q] = pk;
      pk[0] = (f16)cell(B00, cr[4]); pk[1] = (f16)cell(B10, cr[6]);
      *(f16x2*)&Hbuf[1][wb][0][whi][wlo * 16 + c][2 * q] = pk;
      pk[0] = (f16)cell(B01, cr[5]); pk[1] = (f16)cell(B11, cr[7]);
      *(f16x2*)&Hbuf[1][wb][1][whi][wlo * 16 + c][2 * q] = pk;
    }
  };

  // ---------------- observation phase ----------------
#pragma unroll
  for (int t = 0; t < Tobs; ++t) {
    const int rb = t & 1;
    __syncthreads();
    step(rb, rb ^ 1, true, t);
  }

  // ---------------- prediction step 0 (prev disp = 0, plain W_hh) ----------
  ldbias(biasP, bv0, bv1);
  __syncthreads();
  step(0, 1, false, 0);  // s = Tobs: rb=0, wb=1

  // swap to W_eff^T + biasPE
#pragma unroll
  for (int rt = 0; rt < 2; ++rt)
#pragma unroll
    for (int kt = 0; kt < 4; ++kt)
      Wh[rt][kt] = *(const f16x8*)(Wfrag + WF(5 + kt, w, rt, ln));
  ldbias(biasPE, bv0, bv1);

  // disp: 8 threads per (row, jj); thread covers k-slots d_s8*16..+15
  const int d_oi = tid >> 3, d_s8 = tid & 7;
  const int d_row = d_oi >> 1, d_jj = d_oi & 1;   // d_row 0..63
  const int dG = d_row >> 5, drr = d_row & 31;
  const int d_ct = drr >> 4, d_c = drr & 15;
  const int d_kt = d_s8 >> 1, d_fl = (2 * (d_s8 & 1)) * 16 + d_c;
  const float d_bo = b_out[d_jj];

  auto disp_out = [&](int rbuf, int p) {
    const float4* wp = (const float4*)(W_outP + d_jj * 128 + d_s8 * 16);
    float4 w0 = wp[0], w1 = wp[1], w2 = wp[2], w3 = wp[3];
    f16x8 e0 = *(const f16x8*)&Hbuf[dG][rbuf][d_ct][d_kt][d_fl][0];
    f16x8 e1 = *(const f16x8*)&Hbuf[dG][rbuf][d_ct][d_kt][d_fl + 16][0];
    float s = w0.x * (float)e0[0] + w0.y * (float)e0[1] +
              w0.z * (float)e0[2] + w0.w * (float)e0[3] +
              w1.x * (float)e0[4] + w1.y * (float)e0[5] +
              w1.z * (float)e0[6] + w1.w * (float)e0[7] +
              w2.x * (float)e1[0] + w2.y * (float)e1[1] +
              w2.z * (float)e1[2] + w2.w * (float)e1[3] +
              w3.x * (float)e1[4] + w3.y * (float)e1[5] +
              w3.z * (float)e1[6] + w3.w * (float)e1[7];
    s += __shfl_xor(s, 1);
    s += __shfl_xor(s, 2);
    s += __shfl_xor(s, 4);
    if ((tid & 7) == 0)
      out[(size_t)(b0 + d_row) * (PREDL * 2) + p * 2 + d_jj] = s + d_bo;
  };

  // ---------------- prediction steps 1..11 (pure h recurrence) -------------
  for (int p = 1; p < PREDL; ++p) {
    const int rb = p & 1;  // s = Tobs + p, Tobs even
    __syncthreads();
    disp_out(rb, p - 1);   // h_{p-1} lives in Hbuf[*][rb]
    step(rb, rb ^ 1, false, 0);
  }
  __syncthreads();
  disp_out((Tobs + PREDL) & 1, PREDL - 1);  // h_11 in buf 0
}

// ---------------------------------------------------------------------------
extern "C" void kernel_launch(void* const* d_in, const int* in_sizes, int n_in,
                              void* d_out, int out_size, void* d_ws, size_t ws_size,
                              hipStream_t stream) {
  const float* obs   = (const float*)d_in[0];
  const float* nbrs  = (const float*)d_in[1];
  const float* table = (const float*)d_in[2];
  const float* W_in  = (const float*)d_in[3];
  const float* b_in  = (const float*)d_in[4];
  const float* W_sp  = (const float*)d_in[5];
  const float* b_sp  = (const float*)d_in[6];
  const float* W_ih  = (const float*)d_in[7];
  const float* W_hh  = (const float*)d_in[8];
  const float* b_ih  = (const float*)d_in[9];
  const float* b_hh  = (const float*)d_in[10];
  const float* W_out = (const float*)d_in[11];
  const float* b_out = (const float*)d_in[12];
  float* out = (float*)d_out;

  // ws layout (bytes): Wfrag f16[147456] @0 (294912) | biasO @294912 (2048) |
  //   biasP @296960 (2048) | biasPE @299008 (2048) | W_outP @301056 (1024)
  char* ws = (char*)d_ws;
  f16*   Wfrag  = (f16*)(ws);
  float* biasO  = (float*)(ws + 294912);
  float* biasP  = (float*)(ws + 296960);
  float* biasPE = (float*)(ws + 299008);
  float* W_outP = (float*)(ws + 301056);

  pack_all<<<512, 64, 0, stream>>>(W_ih, W_hh, W_in, W_sp, table, b_in, b_sp, b_ih, b_hh,
                                   W_out, b_out, Wfrag, biasO, biasP, biasPE, W_outP);
  social_lstm_main<<<Bsz / MR, 1024, 0, stream>>>(obs, nbrs, Wfrag, biasO, biasP, biasPE,
                                                  W_outP, b_out, out);
}